// Round 2
// baseline (248.335 us; speedup 1.0000x reference)
//
#include <hip/hip_runtime.h>
#include <stdint.h>

#define DIM   2048
#define NEXP  64
#define TPB   64      // tokens per block
#define BK    64      // k-chunk (floats)

__device__ inline uint64_t mono_from_d(double d) {
    uint64_t u = (uint64_t)__double_as_longlong(d);
    return (u >> 63) ? ~u : (u | 0x8000000000000000ull);
}
__device__ inline double d_from_mono(uint64_t u) {
    uint64_t b = (u >> 63) ? (u & 0x7FFFFFFFFFFFFFFFull) : ~u;
    return __longlong_as_double((long long)b);
}

__global__ __launch_bounds__(256) void moe_gate_kernel(
    const float* __restrict__ x, const float* __restrict__ wgt,
    float* __restrict__ out, int ntok)
{
    // lsd: f64 logits [64 tokens][66]; aliased as fp32 staging xs/ws during GEMM
    __shared__ __align__(16) double lsd[TPB][NEXP + 2];       // 33792 B
    float* xs = (float*)&lsd[0][0];                            // [64][64] f32
    float* ws = xs + TPB * BK;                                 // [64][64] f32

    const int tid = threadIdx.x;
    const int t0  = blockIdx.x * TPB;

    const int ti = tid & 15;   // token-tile index   (rows 4*ti..4*ti+3)
    const int ei = tid >> 4;   // expert-tile index  (rows 4*ei..4*ei+3)

    double acc[4][4];
#pragma unroll
    for (int a = 0; a < 4; ++a)
#pragma unroll
        for (int b = 0; b < 4; ++b) acc[a][b] = 0.0;

    const int lrow = tid >> 4;   // staging row within group of 16
    const int lc   = tid & 15;   // 16B slot within row

    for (int k0 = 0; k0 < DIM; k0 += BK) {
        __syncthreads();
        // stage x[64][64] and w[64][64] chunks, swizzled: phys_slot = lc ^ ((row>>2)&7)
#pragma unroll
        for (int it = 0; it < 4; ++it) {
            int row  = it * 16 + lrow;
            int slot = lc ^ ((row >> 2) & 7);
            float4 xv = *(const float4*)(x   + (size_t)(t0 + row) * DIM + k0 + 4 * lc);
            float4 wv = *(const float4*)(wgt + (size_t)row        * DIM + k0 + 4 * lc);
            *(float4*)(&xs[row * BK + 4 * slot]) = xv;
            *(float4*)(&ws[row * BK + 4 * slot]) = wv;
        }
        __syncthreads();
#pragma unroll 4
        for (int k4 = 0; k4 < BK / 4; ++k4) {
            float4 xa[4], wb[4];
#pragma unroll
            for (int j = 0; j < 4; ++j)
                xa[j] = *(const float4*)(&xs[(4 * ti + j) * BK + ((k4 ^ (ti & 7)) << 2)]);
#pragma unroll
            for (int j = 0; j < 4; ++j)
                wb[j] = *(const float4*)(&ws[(4 * ei + j) * BK + ((k4 ^ (ei & 7)) << 2)]);
            // convert once, reuse 4x
            double xd[4][4], wd[4][4];
#pragma unroll
            for (int j = 0; j < 4; ++j) {
                xd[j][0] = (double)xa[j].x; xd[j][1] = (double)xa[j].y;
                xd[j][2] = (double)xa[j].z; xd[j][3] = (double)xa[j].w;
                wd[j][0] = (double)wb[j].x; wd[j][1] = (double)wb[j].y;
                wd[j][2] = (double)wb[j].z; wd[j][3] = (double)wb[j].w;
            }
#pragma unroll
            for (int a = 0; a < 4; ++a)
#pragma unroll
                for (int b = 0; b < 4; ++b) {
                    acc[a][b] = fma(xd[a][0], wd[b][0], acc[a][b]);
                    acc[a][b] = fma(xd[a][1], wd[b][1], acc[a][b]);
                    acc[a][b] = fma(xd[a][2], wd[b][2], acc[a][b]);
                    acc[a][b] = fma(xd[a][3], wd[b][3], acc[a][b]);
                }
        }
    }

    // ---- dump f64 logits to LDS: lsd[token][expert] ----
    __syncthreads();
#pragma unroll
    for (int a = 0; a < 4; ++a) {
        double2 v0; v0.x = acc[a][0]; v0.y = acc[a][1];
        double2 v1; v1.x = acc[a][2]; v1.y = acc[a][3];
        *(double2*)(&lsd[4 * ti + a][4 * ei])     = v0;
        *(double2*)(&lsd[4 * ti + a][4 * ei + 2]) = v1;
    }
    __syncthreads();

    // ---- softmax + top-8: 4 lanes per token, 16 experts each ----
    const int lane = tid & 63;
    const int wv   = tid >> 6;            // wave 0..3
    const int tok  = wv * 16 + (lane & 15);
    const int sub  = lane >> 4;           // 0..3

    double rd[16];
#pragma unroll
    for (int k = 0; k < 8; ++k) {
        double2 v = *(const double2*)(&lsd[tok][sub * 16 + 2 * k]);
        rd[2 * k] = v.x; rd[2 * k + 1] = v.y;
    }
    float r[16];
#pragma unroll
    for (int i = 0; i < 16; ++i) r[i] = (float)rd[i];

    float m = r[0];
#pragma unroll
    for (int i = 1; i < 16; ++i) m = fmaxf(m, r[i]);
    m = fmaxf(m, __shfl_xor(m, 16));
    m = fmaxf(m, __shfl_xor(m, 32));

    float s = 0.f;
#pragma unroll
    for (int i = 0; i < 16; ++i) s += expf(r[i] - m);
    s += __shfl_xor(s, 16);
    s += __shfl_xor(s, 32);

    // top-8 on f64-logit ordering: key = (mono(logit) & ~63) | (63-idx)
    uint64_t prev = ~0ull;
    float ovals[8]; float oidx[8];
#pragma unroll
    for (int p = 0; p < 8; ++p) {
        uint64_t best = 0;
#pragma unroll
        for (int i = 0; i < 16; ++i) {
            uint64_t key = (mono_from_d(rd[i]) & ~63ull)
                         | (uint64_t)(63 - (sub * 16 + i));
            if (key < prev && key > best) best = key;
        }
        {
            unsigned long long o;
            o = __shfl_xor((unsigned long long)best, 16);
            if ((uint64_t)o > best) best = (uint64_t)o;
            o = __shfl_xor((unsigned long long)best, 32);
            if ((uint64_t)o > best) best = (uint64_t)o;
        }
        prev = best;
        int   widx = 63 - (int)(best & 63ull);
        float wlg  = (float)d_from_mono(best & ~63ull);
        ovals[p] = expf(wlg - m) / s;
        oidx[p]  = (float)widx;
    }

    if (sub == 0) {
        size_t gtok = (size_t)(t0 + tok);
        float* vo = out + gtok * 8;
        float* io = out + (size_t)ntok * 8 + gtok * 8;
        *(float4*)(vo)     = make_float4(ovals[0], ovals[1], ovals[2], ovals[3]);
        *(float4*)(vo + 4) = make_float4(ovals[4], ovals[5], ovals[6], ovals[7]);
        *(float4*)(io)     = make_float4(oidx[0], oidx[1], oidx[2], oidx[3]);
        *(float4*)(io + 4) = make_float4(oidx[4], oidx[5], oidx[6], oidx[7]);
    }
}

extern "C" void kernel_launch(void* const* d_in, const int* in_sizes, int n_in,
                              void* d_out, int out_size, void* d_ws, size_t ws_size,
                              hipStream_t stream) {
    const float* x   = (const float*)d_in[0];
    const float* wgt = (const float*)d_in[1];
    float* out = (float*)d_out;
    const int ntok = in_sizes[0] / DIM;   // 32768
    dim3 grid(ntok / TPB), block(256);
    hipLaunchKernelGGL(moe_gate_kernel, grid, block, 0, stream, x, wgt, out, ntok);
}

// Round 6
// 230.547 us; speedup vs baseline: 1.0772x; 1.0772x over previous
//
#include <hip/hip_runtime.h>
#include <stdint.h>

#define DIM   2048
#define NEXP  64
#define TPB   64      // tokens per block (pass 1)
#define BK    64      // k-chunk (floats)
#define LSTR  68      // logits LDS row stride (floats)
#define TAU   1e-4f   // near-tie threshold on relative prob gaps (~30-50x fp32 noise)

__device__ inline uint64_t mono64(double d) {
    uint64_t u = (uint64_t)__double_as_longlong(d);
    return (u >> 63) ? ~u : (u | 0x8000000000000000ull);
}
__device__ inline double unmono64(uint64_t m) {
    uint64_t b = (m >> 63) ? (m & 0x7fffffffffffffffull) : ~m;
    return __longlong_as_double((long long)b);
}

// ---------------- Pass 1: fp32 GEMM + softmax + top-8 + near-tie flag ----------------
__global__ __launch_bounds__(256) void moe_gate_fp32_kernel(
    const float* __restrict__ x, const float* __restrict__ wgt,
    float* __restrict__ out, int ntok, unsigned char* __restrict__ flags)
{
    __shared__ __align__(16) float smem[2 * TPB * BK];   // 32 KB
    float* xs = smem;
    float* ws = smem + TPB * BK;

    const int tid = threadIdx.x;
    const int t0  = blockIdx.x * TPB;

    const int ti = tid & 15;   // token-tile index   (rows 4*ti..4*ti+3)
    const int ei = tid >> 4;   // expert-tile index  (rows 4*ei..4*ei+3)

    float acc[4][4];
#pragma unroll
    for (int a = 0; a < 4; ++a)
#pragma unroll
        for (int b = 0; b < 4; ++b) acc[a][b] = 0.f;

    const int lrow = tid >> 4;
    const int lc   = tid & 15;

    for (int k0 = 0; k0 < DIM; k0 += BK) {
        __syncthreads();
#pragma unroll
        for (int it = 0; it < 4; ++it) {
            int row  = it * 16 + lrow;
            int slot = lc ^ ((row >> 2) & 7);
            float4 xv = *(const float4*)(x   + (size_t)(t0 + row) * DIM + k0 + 4 * lc);
            float4 wv = *(const float4*)(wgt + (size_t)row        * DIM + k0 + 4 * lc);
            *(float4*)(&xs[row * BK + 4 * slot]) = xv;
            *(float4*)(&ws[row * BK + 4 * slot]) = wv;
        }
        __syncthreads();
#pragma unroll 4
        for (int k4 = 0; k4 < BK / 4; ++k4) {
            float4 xa[4], wb[4];
#pragma unroll
            for (int j = 0; j < 4; ++j)
                xa[j] = *(const float4*)(&xs[(4 * ti + j) * BK + ((k4 ^ (ti & 7)) << 2)]);
#pragma unroll
            for (int j = 0; j < 4; ++j)
                wb[j] = *(const float4*)(&ws[(4 * ei + j) * BK + ((k4 ^ (ei & 7)) << 2)]);
#pragma unroll
            for (int a = 0; a < 4; ++a)
#pragma unroll
                for (int b = 0; b < 4; ++b) {
                    acc[a][b] = fmaf(xa[a].x, wb[b].x, acc[a][b]);
                    acc[a][b] = fmaf(xa[a].y, wb[b].y, acc[a][b]);
                    acc[a][b] = fmaf(xa[a].z, wb[b].z, acc[a][b]);
                    acc[a][b] = fmaf(xa[a].w, wb[b].w, acc[a][b]);
                }
        }
    }

    // ---- logits to LDS: ls[token][expert], stride LSTR ----
    __syncthreads();
    float* ls = smem;   // 64*68*4 = 17408 B
#pragma unroll
    for (int a = 0; a < 4; ++a) {
        float4 v = make_float4(acc[a][0], acc[a][1], acc[a][2], acc[a][3]);
        *(float4*)(&ls[(4 * ti + a) * LSTR + 4 * ei]) = v;
    }
    __syncthreads();

    // ---- softmax + top-8: 4 lanes per token, 16 experts each ----
    const int lane = tid & 63;
    const int wv   = tid >> 6;
    const int tok  = wv * 16 + (lane & 15);
    const int sub  = lane >> 4;

    float r[16];
#pragma unroll
    for (int k = 0; k < 4; ++k) {
        float4 v = *(const float4*)(&ls[tok * LSTR + sub * 16 + 4 * k]);
        r[4 * k] = v.x; r[4 * k + 1] = v.y; r[4 * k + 2] = v.z; r[4 * k + 3] = v.w;
    }

    float m = r[0];
#pragma unroll
    for (int i = 1; i < 16; ++i) m = fmaxf(m, r[i]);
    m = fmaxf(m, __shfl_xor(m, 16));
    m = fmaxf(m, __shfl_xor(m, 32));

    float ex[16]; float s = 0.f;
#pragma unroll
    for (int i = 0; i < 16; ++i) { ex[i] = expf(r[i] - m); s += ex[i]; }
    s += __shfl_xor(s, 16);
    s += __shfl_xor(s, 32);

    float pr[16];
#pragma unroll
    for (int i = 0; i < 16; ++i) pr[i] = ex[i] / s;

    // top-8 by (prob desc, index asc): u64 key = prob_bits<<32 | (63-idx)
    uint64_t prev = ~0ull;
    float ovals[8]; float oidx[8];
    float prevp = 0.f; int nearf = 0;
#pragma unroll
    for (int p = 0; p < 8; ++p) {
        uint64_t best = 0;
#pragma unroll
        for (int i = 0; i < 16; ++i) {
            uint64_t key = ((uint64_t)__float_as_uint(pr[i]) << 32)
                         | (uint64_t)(63 - (sub * 16 + i));
            if (key < prev && key > best) best = key;
        }
        {
            uint32_t bh = (uint32_t)(best >> 32), bl = (uint32_t)best;
            uint32_t oh = __shfl_xor(bh, 16), ol = __shfl_xor(bl, 16);
            uint64_t ob = ((uint64_t)oh << 32) | ol;
            if (ob > best) best = ob;
            bh = (uint32_t)(best >> 32); bl = (uint32_t)best;
            oh = __shfl_xor(bh, 32); ol = __shfl_xor(bl, 32);
            ob = ((uint64_t)oh << 32) | ol;
            if (ob > best) best = ob;
        }
        prev = best;
        float pv = __uint_as_float((uint32_t)(best >> 32));
        if (p > 0 && (prevp - pv) < TAU * pv) nearf = 1;
        prevp = pv;
        ovals[p] = pv;
        oidx[p]  = (float)(63 - (int)(best & 63));
    }
    // 9th selection round (same construct) for the boundary gap
    {
        uint64_t best = 0;
#pragma unroll
        for (int i = 0; i < 16; ++i) {
            uint64_t key = ((uint64_t)__float_as_uint(pr[i]) << 32)
                         | (uint64_t)(63 - (sub * 16 + i));
            if (key < prev && key > best) best = key;
        }
        {
            uint32_t bh = (uint32_t)(best >> 32), bl = (uint32_t)best;
            uint32_t oh = __shfl_xor(bh, 16), ol = __shfl_xor(bl, 16);
            uint64_t ob = ((uint64_t)oh << 32) | ol;
            if (ob > best) best = ob;
            bh = (uint32_t)(best >> 32); bl = (uint32_t)best;
            oh = __shfl_xor(bh, 32); ol = __shfl_xor(bl, 32);
            ob = ((uint64_t)oh << 32) | ol;
            if (ob > best) best = ob;
        }
        float pv9 = __uint_as_float((uint32_t)(best >> 32));
        if ((prevp - pv9) < TAU * pv9) nearf = 1;
    }

    if (sub == 0) {
        size_t gtok = (size_t)(t0 + tok);
        float* vo = out + gtok * 8;
        float* io = out + (size_t)ntok * 8 + gtok * 8;
        *(float4*)(vo)     = make_float4(ovals[0], ovals[1], ovals[2], ovals[3]);
        *(float4*)(vo + 4) = make_float4(ovals[4], ovals[5], ovals[6], ovals[7]);
        *(float4*)(io)     = make_float4(oidx[0], oidx[1], oidx[2], oidx[3]);
        *(float4*)(io + 4) = make_float4(oidx[4], oidx[5], oidx[6], oidx[7]);
        flags[gtok] = (unsigned char)nearf;
    }
}

// ------- Pass 2: f64 refinement, 1 wave/token, no LDS, no barriers -------
__global__ __launch_bounds__(64) void moe_gate_refine_kernel(
    const float* __restrict__ x, const float* __restrict__ wgt,
    float* __restrict__ out, int ntok, const unsigned char* __restrict__ flags)
{
    const int lane = threadIdx.x;        // expert id 0..63
    const int base = blockIdx.x * 4;

    for (int t = 0; t < 4; ++t) {
        const int tok = base + t;
        if (flags[tok] == 0) continue;   // wave-uniform

        const float* xp = x   + (size_t)tok  * DIM;
        const float* wp = wgt + (size_t)lane * DIM;
        double acc = 0.0;
        for (int k = 0; k < DIM; k += 4) {
            float4 xv = *(const float4*)(xp + k);
            float4 wv = *(const float4*)(wp + k);
            acc = fma((double)xv.x, (double)wv.x, acc);
            acc = fma((double)xv.y, (double)wv.y, acc);
            acc = fma((double)xv.z, (double)wv.z, acc);
            acc = fma((double)xv.w, (double)wv.w, acc);
        }

        uint64_t mykey = (mono64(acc) & ~63ull) | (uint64_t)(63 - lane);

        // wave-max of keys -> running max logit
        uint64_t mk = mykey;
        {
            unsigned long long o;
            o = __shfl_xor((unsigned long long)mk, 1);  if ((uint64_t)o > mk) mk = (uint64_t)o;
            o = __shfl_xor((unsigned long long)mk, 2);  if ((uint64_t)o > mk) mk = (uint64_t)o;
            o = __shfl_xor((unsigned long long)mk, 4);  if ((uint64_t)o > mk) mk = (uint64_t)o;
            o = __shfl_xor((unsigned long long)mk, 8);  if ((uint64_t)o > mk) mk = (uint64_t)o;
            o = __shfl_xor((unsigned long long)mk, 16); if ((uint64_t)o > mk) mk = (uint64_t)o;
            o = __shfl_xor((unsigned long long)mk, 32); if ((uint64_t)o > mk) mk = (uint64_t)o;
        }
        double md = unmono64(mk & ~63ull);

        float s = expf((float)(acc - md));
        s += __shfl_xor(s, 1);
        s += __shfl_xor(s, 2);
        s += __shfl_xor(s, 4);
        s += __shfl_xor(s, 8);
        s += __shfl_xor(s, 16);
        s += __shfl_xor(s, 32);

        float* vo = out + (size_t)tok * 8;
        float* io = out + (size_t)ntok * 8 + (size_t)tok * 8;

        uint64_t prev = ~0ull;
        for (int q = 0; q < 8; ++q) {
            uint64_t best = (mykey < prev) ? mykey : 0;
            {
                unsigned long long o;
                o = __shfl_xor((unsigned long long)best, 1);  if ((uint64_t)o > best) best = (uint64_t)o;
                o = __shfl_xor((unsigned long long)best, 2);  if ((uint64_t)o > best) best = (uint64_t)o;
                o = __shfl_xor((unsigned long long)best, 4);  if ((uint64_t)o > best) best = (uint64_t)o;
                o = __shfl_xor((unsigned long long)best, 8);  if ((uint64_t)o > best) best = (uint64_t)o;
                o = __shfl_xor((unsigned long long)best, 16); if ((uint64_t)o > best) best = (uint64_t)o;
                o = __shfl_xor((unsigned long long)best, 32); if ((uint64_t)o > best) best = (uint64_t)o;
            }
            prev = best;
            if (lane == 0) {
                vo[q] = expf((float)(unmono64(best & ~63ull) - md)) / s;
                io[q] = (float)(63 - (int)(best & 63ull));
            }
        }
    }
}

extern "C" void kernel_launch(void* const* d_in, const int* in_sizes, int n_in,
                              void* d_out, int out_size, void* d_ws, size_t ws_size,
                              hipStream_t stream) {
    const float* x   = (const float*)d_in[0];
    const float* wgt = (const float*)d_in[1];
    float* out = (float*)d_out;
    const int ntok = in_sizes[0] / DIM;   // 32768
    unsigned char* flags = (unsigned char*)d_ws;   // ntok bytes (32 KB)

    hipLaunchKernelGGL(moe_gate_fp32_kernel, dim3(ntok / TPB), dim3(256), 0, stream,
                       x, wgt, out, ntok, flags);
    hipLaunchKernelGGL(moe_gate_refine_kernel, dim3(ntok / 4), dim3(64), 0, stream,
                       x, wgt, out, ntok, flags);
}

// Round 7
// 189.310 us; speedup vs baseline: 1.3118x; 1.2178x over previous
//
#include <hip/hip_runtime.h>
#include <stdint.h>

#define DIM   2048
#define NEXP  64
#define TPB   64      // tokens per block (pass 1)
#define LSTR  68      // logits LDS row stride (floats)
#define TAU   2e-4f   // near-tie threshold on relative prob gaps (bf16x3 noise ~1e-5 tail)

typedef __attribute__((ext_vector_type(8))) short bf16x8;
typedef __attribute__((ext_vector_type(8))) unsigned short u16x8;
typedef __attribute__((ext_vector_type(4))) float f32x4;

__device__ inline unsigned short bf16_rne(float f) {
    uint32_t u = __float_as_uint(f);
    return (unsigned short)((u + 0x7FFFu + ((u >> 16) & 1u)) >> 16);
}
__device__ inline float bf16_to_f(unsigned short h) {
    return __uint_as_float(((uint32_t)h) << 16);
}

__device__ inline uint64_t mono64(double d) {
    uint64_t u = (uint64_t)__double_as_longlong(d);
    return (u >> 63) ? ~u : (u | 0x8000000000000000ull);
}
__device__ inline double unmono64(uint64_t m) {
    uint64_t b = (m >> 63) ? (m & 0x7fffffffffffffffull) : ~m;
    return __longlong_as_double((long long)b);
}

#define SPL(F, HV, LV, J) { unsigned short _h = bf16_rne(F); HV[J] = _h; LV[J] = bf16_rne((F) - bf16_to_f(_h)); }

// ---------------- Pass 1: bf16x3 MFMA GEMM + softmax + top-8 + near-tie flag ----------------
__global__ __launch_bounds__(256) void moe_gate_mfma_kernel(
    const float* __restrict__ x, const float* __restrict__ wgt,
    float* __restrict__ out, int ntok, unsigned char* __restrict__ flags)
{
    // 32 KB: xh[64][64] | xl[64][64] | wh[64][64] | wl[64][64]  (ushort units)
    __shared__ __align__(16) unsigned short smem_u[4 * 64 * 64];

    const int tid  = threadIdx.x;
    const int t0   = blockIdx.x * TPB;
    const int lane = tid & 63;
    const int ww   = tid >> 6;

    // staging geometry: thread -> (row 0..63, quarter 0..3); 16B slots XOR-swizzled by row
    const int srow  = tid >> 2;
    const int sq    = tid & 3;
    const int s7    = srow & 7;
    const int ps0   = ((2 * sq)     ^ s7) * 8;
    const int ps1   = ((2 * sq + 1) ^ s7) * 8;
    const int sbase = srow * 64;

    const float* xp = x   + (size_t)(t0 + srow) * DIM + sq * 16;
    const float* wp = wgt + (size_t)srow        * DIM + sq * 16;

    f32x4 acc0 = {0.f,0.f,0.f,0.f}, acc1 = {0.f,0.f,0.f,0.f};
    f32x4 acc2 = {0.f,0.f,0.f,0.f}, acc3 = {0.f,0.f,0.f,0.f};

    const int l15  = lane & 15;
    const int lg   = lane >> 4;
    const int l7   = lane & 7;
    const int arow = ww * 16 + l15;

    for (int k0 = 0; k0 < DIM; k0 += 64) {
        __syncthreads();
        // ---- stage x split ----
        {
            float4 f0 = *(const float4*)(xp + k0 + 0);
            float4 f1 = *(const float4*)(xp + k0 + 4);
            float4 f2 = *(const float4*)(xp + k0 + 8);
            float4 f3 = *(const float4*)(xp + k0 + 12);
            u16x8 h01, l01, h23, l23;
            SPL(f0.x, h01, l01, 0) SPL(f0.y, h01, l01, 1) SPL(f0.z, h01, l01, 2) SPL(f0.w, h01, l01, 3)
            SPL(f1.x, h01, l01, 4) SPL(f1.y, h01, l01, 5) SPL(f1.z, h01, l01, 6) SPL(f1.w, h01, l01, 7)
            SPL(f2.x, h23, l23, 0) SPL(f2.y, h23, l23, 1) SPL(f2.z, h23, l23, 2) SPL(f2.w, h23, l23, 3)
            SPL(f3.x, h23, l23, 4) SPL(f3.y, h23, l23, 5) SPL(f3.z, h23, l23, 6) SPL(f3.w, h23, l23, 7)
            *(u16x8*)(smem_u + sbase + ps0)        = h01;
            *(u16x8*)(smem_u + sbase + ps1)        = h23;
            *(u16x8*)(smem_u + 4096 + sbase + ps0) = l01;
            *(u16x8*)(smem_u + 4096 + sbase + ps1) = l23;
        }
        // ---- stage w split ----
        {
            float4 f0 = *(const float4*)(wp + k0 + 0);
            float4 f1 = *(const float4*)(wp + k0 + 4);
            float4 f2 = *(const float4*)(wp + k0 + 8);
            float4 f3 = *(const float4*)(wp + k0 + 12);
            u16x8 h01, l01, h23, l23;
            SPL(f0.x, h01, l01, 0) SPL(f0.y, h01, l01, 1) SPL(f0.z, h01, l01, 2) SPL(f0.w, h01, l01, 3)
            SPL(f1.x, h01, l01, 4) SPL(f1.y, h01, l01, 5) SPL(f1.z, h01, l01, 6) SPL(f1.w, h01, l01, 7)
            SPL(f2.x, h23, l23, 0) SPL(f2.y, h23, l23, 1) SPL(f2.z, h23, l23, 2) SPL(f2.w, h23, l23, 3)
            SPL(f3.x, h23, l23, 4) SPL(f3.y, h23, l23, 5) SPL(f3.z, h23, l23, 6) SPL(f3.w, h23, l23, 7)
            *(u16x8*)(smem_u + 8192  + sbase + ps0) = h01;
            *(u16x8*)(smem_u + 8192  + sbase + ps1) = h23;
            *(u16x8*)(smem_u + 12288 + sbase + ps0) = l01;
            *(u16x8*)(smem_u + 12288 + sbase + ps1) = l23;
        }
        __syncthreads();

        // ---- compute: 2 K-substeps of 32, 4 N-tiles, products hh + hl + lh ----
#pragma unroll
        for (int ks = 0; ks < 2; ++ks) {
            const int phys = ((ks << 2) + lg) ^ l7;
            const int aoff = arow * 64 + phys * 8;
            bf16x8 Ah = *(const bf16x8*)(smem_u + aoff);
            bf16x8 Al = *(const bf16x8*)(smem_u + 4096 + aoff);
            const int boff = l15 * 64 + phys * 8 + 8192;
            {
                bf16x8 Bh = *(const bf16x8*)(smem_u + boff);
                bf16x8 Bl = *(const bf16x8*)(smem_u + boff + 4096);
                acc0 = __builtin_amdgcn_mfma_f32_16x16x32_bf16(Ah, Bh, acc0, 0, 0, 0);
                acc0 = __builtin_amdgcn_mfma_f32_16x16x32_bf16(Ah, Bl, acc0, 0, 0, 0);
                acc0 = __builtin_amdgcn_mfma_f32_16x16x32_bf16(Al, Bh, acc0, 0, 0, 0);
            }
            {
                bf16x8 Bh = *(const bf16x8*)(smem_u + boff + 1024);
                bf16x8 Bl = *(const bf16x8*)(smem_u + boff + 1024 + 4096);
                acc1 = __builtin_amdgcn_mfma_f32_16x16x32_bf16(Ah, Bh, acc1, 0, 0, 0);
                acc1 = __builtin_amdgcn_mfma_f32_16x16x32_bf16(Ah, Bl, acc1, 0, 0, 0);
                acc1 = __builtin_amdgcn_mfma_f32_16x16x32_bf16(Al, Bh, acc1, 0, 0, 0);
            }
            {
                bf16x8 Bh = *(const bf16x8*)(smem_u + boff + 2048);
                bf16x8 Bl = *(const bf16x8*)(smem_u + boff + 2048 + 4096);
                acc2 = __builtin_amdgcn_mfma_f32_16x16x32_bf16(Ah, Bh, acc2, 0, 0, 0);
                acc2 = __builtin_amdgcn_mfma_f32_16x16x32_bf16(Ah, Bl, acc2, 0, 0, 0);
                acc2 = __builtin_amdgcn_mfma_f32_16x16x32_bf16(Al, Bh, acc2, 0, 0, 0);
            }
            {
                bf16x8 Bh = *(const bf16x8*)(smem_u + boff + 3072);
                bf16x8 Bl = *(const bf16x8*)(smem_u + boff + 3072 + 4096);
                acc3 = __builtin_amdgcn_mfma_f32_16x16x32_bf16(Ah, Bh, acc3, 0, 0, 0);
                acc3 = __builtin_amdgcn_mfma_f32_16x16x32_bf16(Ah, Bl, acc3, 0, 0, 0);
                acc3 = __builtin_amdgcn_mfma_f32_16x16x32_bf16(Al, Bh, acc3, 0, 0, 0);
            }
        }
    }

    // ---- logits to LDS: ls[token][expert], stride LSTR ----
    __syncthreads();
    float* ls = (float*)smem_u;   // 64*68*4 = 17408 B <= 32768
    {
        const int rbase = ww * 16 + lg * 4;
        ls[(rbase + 0) * LSTR +  0 + l15] = acc0[0];
        ls[(rbase + 1) * LSTR +  0 + l15] = acc0[1];
        ls[(rbase + 2) * LSTR +  0 + l15] = acc0[2];
        ls[(rbase + 3) * LSTR +  0 + l15] = acc0[3];
        ls[(rbase + 0) * LSTR + 16 + l15] = acc1[0];
        ls[(rbase + 1) * LSTR + 16 + l15] = acc1[1];
        ls[(rbase + 2) * LSTR + 16 + l15] = acc1[2];
        ls[(rbase + 3) * LSTR + 16 + l15] = acc1[3];
        ls[(rbase + 0) * LSTR + 32 + l15] = acc2[0];
        ls[(rbase + 1) * LSTR + 32 + l15] = acc2[1];
        ls[(rbase + 2) * LSTR + 32 + l15] = acc2[2];
        ls[(rbase + 3) * LSTR + 32 + l15] = acc2[3];
        ls[(rbase + 0) * LSTR + 48 + l15] = acc3[0];
        ls[(rbase + 1) * LSTR + 48 + l15] = acc3[1];
        ls[(rbase + 2) * LSTR + 48 + l15] = acc3[2];
        ls[(rbase + 3) * LSTR + 48 + l15] = acc3[3];
    }
    __syncthreads();

    // ---- softmax + top-8: 4 lanes per token, 16 experts each (R6 construct) ----
    const int tok = ww * 16 + l15;
    const int sub = lg;

    float r[16];
#pragma unroll
    for (int k = 0; k < 4; ++k) {
        float4 v = *(const float4*)(&ls[tok * LSTR + sub * 16 + 4 * k]);
        r[4 * k] = v.x; r[4 * k + 1] = v.y; r[4 * k + 2] = v.z; r[4 * k + 3] = v.w;
    }

    float m = r[0];
#pragma unroll
    for (int i = 1; i < 16; ++i) m = fmaxf(m, r[i]);
    m = fmaxf(m, __shfl_xor(m, 16));
    m = fmaxf(m, __shfl_xor(m, 32));

    float ex[16]; float s = 0.f;
#pragma unroll
    for (int i = 0; i < 16; ++i) { ex[i] = expf(r[i] - m); s += ex[i]; }
    s += __shfl_xor(s, 16);
    s += __shfl_xor(s, 32);

    float pr[16];
#pragma unroll
    for (int i = 0; i < 16; ++i) pr[i] = ex[i] / s;

    // top-8 by (prob desc, index asc): u64 key = prob_bits<<32 | (63-idx)
    uint64_t prev = ~0ull;
    float ovals[8]; float oidx[8];
    float prevp = 0.f; int nearf = 0;
#pragma unroll
    for (int p = 0; p < 8; ++p) {
        uint64_t best = 0;
#pragma unroll
        for (int i = 0; i < 16; ++i) {
            uint64_t key = ((uint64_t)__float_as_uint(pr[i]) << 32)
                         | (uint64_t)(63 - (sub * 16 + i));
            if (key < prev && key > best) best = key;
        }
        {
            uint32_t bh = (uint32_t)(best >> 32), bl = (uint32_t)best;
            uint32_t oh = __shfl_xor(bh, 16), ol = __shfl_xor(bl, 16);
            uint64_t ob = ((uint64_t)oh << 32) | ol;
            if (ob > best) best = ob;
            bh = (uint32_t)(best >> 32); bl = (uint32_t)best;
            oh = __shfl_xor(bh, 32); ol = __shfl_xor(bl, 32);
            ob = ((uint64_t)oh << 32) | ol;
            if (ob > best) best = ob;
        }
        prev = best;
        float pv = __uint_as_float((uint32_t)(best >> 32));
        if (p > 0 && (prevp - pv) < TAU * pv) nearf = 1;
        prevp = pv;
        ovals[p] = pv;
        oidx[p]  = (float)(63 - (int)(best & 63));
    }
    // 9th selection round (same construct) for the boundary gap
    {
        uint64_t best = 0;
#pragma unroll
        for (int i = 0; i < 16; ++i) {
            uint64_t key = ((uint64_t)__float_as_uint(pr[i]) << 32)
                         | (uint64_t)(63 - (sub * 16 + i));
            if (key < prev && key > best) best = key;
        }
        {
            uint32_t bh = (uint32_t)(best >> 32), bl = (uint32_t)best;
            uint32_t oh = __shfl_xor(bh, 16), ol = __shfl_xor(bl, 16);
            uint64_t ob = ((uint64_t)oh << 32) | ol;
            if (ob > best) best = ob;
            bh = (uint32_t)(best >> 32); bl = (uint32_t)best;
            oh = __shfl_xor(bh, 32); ol = __shfl_xor(bl, 32);
            ob = ((uint64_t)oh << 32) | ol;
            if (ob > best) best = ob;
        }
        float pv9 = __uint_as_float((uint32_t)(best >> 32));
        if ((prevp - pv9) < TAU * pv9) nearf = 1;
    }

    if (sub == 0) {
        size_t gtok = (size_t)(t0 + tok);
        float* vo = out + gtok * 8;
        float* io = out + (size_t)ntok * 8 + gtok * 8;
        *(float4*)(vo)     = make_float4(ovals[0], ovals[1], ovals[2], ovals[3]);
        *(float4*)(vo + 4) = make_float4(ovals[4], ovals[5], ovals[6], ovals[7]);
        *(float4*)(io)     = make_float4(oidx[0], oidx[1], oidx[2], oidx[3]);
        *(float4*)(io + 4) = make_float4(oidx[4], oidx[5], oidx[6], oidx[7]);
        flags[gtok] = (unsigned char)nearf;
    }
}

// ------- Pass 2: f64 refinement, 1 wave/token, no LDS, no barriers (R6 verbatim) -------
__global__ __launch_bounds__(64) void moe_gate_refine_kernel(
    const float* __restrict__ x, const float* __restrict__ wgt,
    float* __restrict__ out, int ntok, const unsigned char* __restrict__ flags)
{
    const int lane = threadIdx.x;        // expert id 0..63
    const int base = blockIdx.x * 4;

    for (int t = 0; t < 4; ++t) {
        const int tok = base + t;
        if (flags[tok] == 0) continue;   // wave-uniform

        const float* xp = x   + (size_t)tok  * DIM;
        const float* wp = wgt + (size_t)lane * DIM;
        double acc = 0.0;
        for (int k = 0; k < DIM; k += 4) {
            float4 xv = *(const float4*)(xp + k);
            float4 wv = *(const float4*)(wp + k);
            acc = fma((double)xv.x, (double)wv.x, acc);
            acc = fma((double)xv.y, (double)wv.y, acc);
            acc = fma((double)xv.z, (double)wv.z, acc);
            acc = fma((double)xv.w, (double)wv.w, acc);
        }

        uint64_t mykey = (mono64(acc) & ~63ull) | (uint64_t)(63 - lane);

        uint64_t mk = mykey;
        {
            unsigned long long o;
            o = __shfl_xor((unsigned long long)mk, 1);  if ((uint64_t)o > mk) mk = (uint64_t)o;
            o = __shfl_xor((unsigned long long)mk, 2);  if ((uint64_t)o > mk) mk = (uint64_t)o;
            o = __shfl_xor((unsigned long long)mk, 4);  if ((uint64_t)o > mk) mk = (uint64_t)o;
            o = __shfl_xor((unsigned long long)mk, 8);  if ((uint64_t)o > mk) mk = (uint64_t)o;
            o = __shfl_xor((unsigned long long)mk, 16); if ((uint64_t)o > mk) mk = (uint64_t)o;
            o = __shfl_xor((unsigned long long)mk, 32); if ((uint64_t)o > mk) mk = (uint64_t)o;
        }
        double md = unmono64(mk & ~63ull);

        float s = expf((float)(acc - md));
        s += __shfl_xor(s, 1);
        s += __shfl_xor(s, 2);
        s += __shfl_xor(s, 4);
        s += __shfl_xor(s, 8);
        s += __shfl_xor(s, 16);
        s += __shfl_xor(s, 32);

        float* vo = out + (size_t)tok * 8;
        float* io = out + (size_t)ntok * 8 + (size_t)tok * 8;

        uint64_t prev = ~0ull;
        for (int q = 0; q < 8; ++q) {
            uint64_t best = (mykey < prev) ? mykey : 0;
            {
                unsigned long long o;
                o = __shfl_xor((unsigned long long)best, 1);  if ((uint64_t)o > best) best = (uint64_t)o;
                o = __shfl_xor((unsigned long long)best, 2);  if ((uint64_t)o > best) best = (uint64_t)o;
                o = __shfl_xor((unsigned long long)best, 4);  if ((uint64_t)o > best) best = (uint64_t)o;
                o = __shfl_xor((unsigned long long)best, 8);  if ((uint64_t)o > best) best = (uint64_t)o;
                o = __shfl_xor((unsigned long long)best, 16); if ((uint64_t)o > best) best = (uint64_t)o;
                o = __shfl_xor((unsigned long long)best, 32); if ((uint64_t)o > best) best = (uint64_t)o;
            }
            prev = best;
            if (lane == 0) {
                vo[q] = expf((float)(unmono64(best & ~63ull) - md)) / s;
                io[q] = (float)(63 - (int)(best & 63ull));
            }
        }
    }
}

extern "C" void kernel_launch(void* const* d_in, const int* in_sizes, int n_in,
                              void* d_out, int out_size, void* d_ws, size_t ws_size,
                              hipStream_t stream) {
    const float* x   = (const float*)d_in[0];
    const float* wgt = (const float*)d_in[1];
    float* out = (float*)d_out;
    const int ntok = in_sizes[0] / DIM;   // 32768
    unsigned char* flags = (unsigned char*)d_ws;   // ntok bytes (32 KB)

    hipLaunchKernelGGL(moe_gate_mfma_kernel, dim3(ntok / TPB), dim3(256), 0, stream,
                       x, wgt, out, ntok, flags);
    hipLaunchKernelGGL(moe_gate_refine_kernel, dim3(ntok / 4), dim3(64), 0, stream,
                       x, wgt, out, ntok, flags);
}